// Round 25
// baseline (105.420 us; speedup 1.0000x reference)
//
#include <hip/hip_runtime.h>

#define TT   2048
#define BB   8
#define DD   1024
#define HD   64        // head dim d
#define MP1  9         // NM + 1
#define NTOK (TT*BB)   // 16384
#define CH   64        // chunk length
#define NC   32        // max chunks per segment
#define NSEG (BB*MP1)  // 72 segments
#define SEGCAP 2048    // max packed positions per segment
#define NCAT 1280      // 64 Q + 576 K + 576 V + 64 pad (bcat layout)
#define LDP  72        // padded LDS row stride (16B-aligned)
#define NZB  1024      // zero-out blocks (4MB / (256*16B))

typedef __attribute__((ext_vector_type(8))) short bf16x8;
typedef __attribute__((ext_vector_type(4))) float f32x4;

union U8 { uint4 v; unsigned short s[8]; };

static __device__ __forceinline__ unsigned short f2bf(float f) {
  union { float f; unsigned u; } c; c.f = f;
  unsigned r = (c.u + 0x7FFF + ((c.u >> 16) & 1)) >> 16;   // RNE
  return (unsigned short)r;
}
static __device__ __forceinline__ float bf2f(unsigned short s) {
  union { unsigned u; float f; } c; c.u = ((unsigned)s) << 16;
  return c.f;
}

// schedule walk: flat bid -> (seg, chunk) with batch = bid&7 pinned to XCD
static __device__ __forceinline__ int sched_walk(
    const int* __restrict__ seglen, int bid, int* chunk_out) {
  const int batch = bid & 7;
  int idx = bid >> 3;
  for (int m = 0; m < MP1; m++) {
    int nch = (seglen[batch * MP1 + m] + 63) >> 6;
    if (idx < nch) { *chunk_out = idx; return batch * MP1 + m; }
    idx -= nch;
  }
  return -1;
}

// ---------------------------------------------------------------
// prep (fused, R12): [0,320) weight transpose/cast + bcat;
// [320,1344) gating + X->bf16 batch-major (vectorized Wg staging);
// [1344,2368) zero d_out.
// ---------------------------------------------------------------
__global__ __launch_bounds__(256) void prep(
    const float* __restrict__ X,
    const float* __restrict__ Wq, const float* __restrict__ Wk,
    const float* __restrict__ Wv, const float* __restrict__ bq,
    const float* __restrict__ bk, const float* __restrict__ bv,
    const float* __restrict__ Wg, const float* __restrict__ bg,
    unsigned short* __restrict__ Wt, float* __restrict__ bcat,
    int2* __restrict__ idxb, float2* __restrict__ alfb,
    unsigned short* __restrict__ Xb,
    float4* __restrict__ outz, int n4) {
  __shared__ float smem[8 * DD];
  const int tid = threadIdx.x;
  const int id = blockIdx.x;
  if (id >= 1344) {                         // zero d_out
    int i = (id - 1344) * 256 + tid;
    if (i < n4) outz[i] = make_float4(0.f, 0.f, 0.f, 0.f);
    return;
  }
  if (id < 320) {
    float (*tile)[65] = (float(*)[65])smem;
    const int n0 = (id % 20) * 64, k0 = (id / 20) * 64;
    const int c = tid & 63, rr = tid >> 6;
#pragma unroll 4
    for (int i = 0; i < 16; i++) {
      int kk = k0 + rr * 16 + i;
      int n  = n0 + c;
      float v = 0.f;
      if (n0 < 64)        v = Wq[kk * 64 + n];
      else if (n0 < 640)  v = Wk[kk * 576 + (n - 64)];
      else if (n0 < 1216) v = Wv[kk * 576 + (n - 640)];
      tile[rr * 16 + i][c] = v;
    }
    __syncthreads();
    const int lk = (tid & 15) * 4, ln = tid >> 4;
#pragma unroll
    for (int p = 0; p < 4; p++) {
      int nl = p * 16 + ln;
      ushort4 o;
      o.x = f2bf(tile[lk + 0][nl]); o.y = f2bf(tile[lk + 1][nl]);
      o.z = f2bf(tile[lk + 2][nl]); o.w = f2bf(tile[lk + 3][nl]);
      *(ushort4*)&Wt[(size_t)(n0 + nl) * DD + k0 + lk] = o;
    }
    if (id == 0) {
      for (int idx = tid; idx < NCAT; idx += 256) {
        float b = 0.f;
        if (idx < 64)        b = bq[idx];
        else if (idx < 640)  b = bk[idx - 64];
        else if (idx < 1216) b = bv[idx - 640];
        bcat[idx] = b;
      }
    }
    return;
  }
  // gating: vectorized Wg staging (8 coalesced float4 rounds)
  float* wgT = smem;
#pragma unroll
  for (int idx4 = tid; idx4 < 2048; idx4 += 256) {
    float4 v = *(const float4*)&Wg[(size_t)idx4 * 4];
    int flat = idx4 * 4;
    int i = flat >> 3, j = flat & 7;        // j in {0,4}
    wgT[(j + 0) * DD + i] = v.x;
    wgT[(j + 1) * DD + i] = v.y;
    wgT[(j + 2) * DD + i] = v.z;
    wgT[(j + 3) * DD + i] = v.w;
  }
  __syncthreads();
  const int lane = tid & 63, wave = tid >> 6;
  const int base_tok = (id - 320) * 16 + wave * 4;
  for (int tk = 0; tk < 4; tk++) {
    const int tok = base_tok + tk;                   // tok = t*BB + b
    const float* xr = X + (size_t)tok * DD;
    unsigned short* xbr = Xb + ((size_t)((tok & 7) * TT + (tok >> 3))) * DD;
    float p[8] = {0.f,0.f,0.f,0.f,0.f,0.f,0.f,0.f};
#pragma unroll
    for (int it = 0; it < 4; it++) {
      int i = it * 256 + lane * 4;
      float4 x = *(const float4*)&xr[i];
      ushort4 o;
      o.x = f2bf(x.x); o.y = f2bf(x.y); o.z = f2bf(x.z); o.w = f2bf(x.w);
      *(ushort4*)&xbr[i] = o;
#pragma unroll
      for (int j = 0; j < 8; j++) {
        float4 wv = *(const float4*)&wgT[j * DD + i];
        p[j] += x.x * wv.x + x.y * wv.y + x.z * wv.z + x.w * wv.w;
      }
    }
#pragma unroll
    for (int j = 0; j < 8; j++) {
      float v = p[j];
#pragma unroll
      for (int off = 32; off > 0; off >>= 1) v += __shfl_xor(v, off);
      p[j] = v + bg[j];
    }
    if (lane == 0) {
      int i1 = 0; float z1 = p[0];
#pragma unroll
      for (int j = 1; j < 8; j++) if (p[j] > z1) { z1 = p[j]; i1 = j; }
      int i2 = -1; float z2 = -3.0e38f;
#pragma unroll
      for (int j = 0; j < 8; j++) if (j != i1 && p[j] > z2) { z2 = p[j]; i2 = j; }
      float e   = expf(z2 - z1);
      float inv = 1.0f / (1.0f + e);
      idxb[tok] = make_int2(i1 + 1, i2 + 1);
      alfb[tok] = make_float2(inv, e * inv);
    }
  }
}

// ---------------------------------------------------------------
// pack: per segment (b,m), time-ordered routed token list.
// 1024 threads (16 waves): 2 serial rounds; bit-identical output.
// ---------------------------------------------------------------
__global__ __launch_bounds__(1024) void pack_kernel(
    const int2* __restrict__ idxb, const float2* __restrict__ alfb,
    int* __restrict__ tlist, float* __restrict__ alist,
    int* __restrict__ seglen) {
  const int seg = blockIdx.x;
  const int b = seg / MP1, m = seg % MP1;
  const int tid = threadIdx.x;
  int* tl = tlist + (size_t)seg * SEGCAP;
  float* al = alist + (size_t)seg * SEGCAP;
  if (m == 0) {
    for (int pos = tid; pos < TT; pos += 1024) { tl[pos] = pos; al[pos] = 1.f; }
    if (tid == 0) seglen[seg] = TT;
    return;
  }
  __shared__ int wsum[16];
  const int lane = tid & 63, w = tid >> 6;
  int base = 0;
  for (int r = 0; r < TT / 1024; r++) {
    int t = r * 1024 + tid;
    int2 ix = idxb[t * BB + b];
    bool f = (ix.x == m || ix.y == m);
    float2 af = alfb[t * BB + b];
    float alpha = (ix.x == m) ? af.x : af.y;
    unsigned long long mask = __ballot(f);
    int lanepos = __popcll(mask & ((1ull << lane) - 1ull));
    if (lane == 0) wsum[w] = __popcll(mask);
    __syncthreads();
    int wbase = 0, total = 0;
#pragma unroll
    for (int i = 0; i < 16; i++) { int v = wsum[i]; if (i < w) wbase += v; total += v; }
    if (f) { int pos = base + wbase + lanepos; tl[pos] = t; al[pos] = alpha; }
    base += total;
    __syncthreads();
  }
  if (tid == 0) seglen[seg] = base;
  int Lpad = (base + 63) & ~63;               // pad to GEMM M-tile (BM=64)
  for (int pos = base + tid; pos < Lpad; pos += 1024) { tl[pos] = 0; al[pos] = 0.f; }
}

// ---------------------------------------------------------------
// pkv_intra (FUSED, 512-thread / 8-wave, LDS-traffic-balanced):
// GEMM compute remapped: 192 output cols (K|V|Q) = 12 x 16-col
// fragments; wave (rh = w>>2, g = w&3) owns 32 rows x 3 fragments
// -> ds_reads per CMP drop 14 -> 10 b128 per wave (A 2x2 + B 3x2),
// cutting the LDS-BW critical path ~29%. Same 6 MFMA/slab, same
// per-output ordered MFMA chain and swizzled inputs -> bit-identical.
// Staging (wave -> array x k-slab, vmcnt(4)) and intra split (waves
// 4-7 part A, 0-3 part B) unchanged from R22.
// ---------------------------------------------------------------
#define ABUF_H 4096
#define BBUF_H 12288

__global__ __launch_bounds__(512) void pkv_intra(
    const unsigned short* __restrict__ Xb, const unsigned short* __restrict__ Wt,
    const float* __restrict__ bcat,
    const int* __restrict__ tlist, const float* __restrict__ alist,
    const int* __restrict__ seglen,
    unsigned short* __restrict__ Sb16, unsigned short* __restrict__ Qd,
    float* __restrict__ out) {
  int chunk;
  const int seg = sched_walk(seglen, blockIdx.x, &chunk);
  if (seg < 0) return;
  const int t0 = chunk * 64;
  const int L = seglen[seg];
  const int b = seg / MP1, m = seg % MP1;
  __shared__ unsigned short lds[2 * (ABUF_H + BBUF_H)];   // 64 KB, reused
  __shared__ int tls[64];
  unsigned short* Asb = lds;
  unsigned short* Bsb = lds + 2 * ABUF_H;
  const int tid = threadIdx.x;
  const int lane = tid & 63, w = tid >> 6;          // w in [0,8)
  if (tid < 64) tls[tid] = tlist[(size_t)seg * SEGCAP + t0 + tid];
  __syncthreads();

  // ---- staging assignment: wave -> (array, k-slab) ----
  const int arr = w >> 1;            // 0=A, 1=K, 2=V, 3=Q
  const int sl  = w & 1;             // 32-col k-slab within the 64-tile
  const int lk  = (((lane & 3) ^ ((lane >> 3) & 3))) * 8;  // inverse-swizzled src slot
  const unsigned short* src[4];
#pragma unroll
  for (int i = 0; i < 4; i++) {
    int row = i * 16 + (lane >> 2);
    const unsigned short* p;
    if (arr == 0)      p = Xb + ((size_t)b * TT + tls[row]) * DD;
    else if (arr == 1) p = Wt + (size_t)(64  + m * 64 + row) * DD;
    else if (arr == 2) p = Wt + (size_t)(640 + m * 64 + row) * DD;
    else               p = Wt + (size_t)(row) * DD;
    src[i] = p + sl * 32 + lk;
  }
  const int dstoff = (arr == 0) ? (sl * 2048) : ((arr - 1) * 4096 + sl * 2048);

  // ---- compute assignment: wave -> (32-row half, 3-fragment group) ----
  const int rh = w >> 2;             // row half: rows 32*rh .. 32*rh+31
  const int g  = w & 3;              // fragment group: fragments 3g..3g+2
  const int quad = lane >> 4, l15 = lane & 15;
  const int qs   = quad ^ ((l15 >> 1) & 3);   // swizzled read slot

  // per-fragment bias (col192 = f*16 + l15; sections K|V|Q at 0/64/128)
  float biasf[3];
#pragma unroll
  for (int fi = 0; fi < 3; fi++) {
    int f = 3 * g + fi;
    int cl = (f & 3) * 16 + l15;               // within-section col
    biasf[fi] = (f < 4) ? bcat[64 + m * 64 + cl]
              : (f < 8) ? bcat[640 + m * 64 + cl]
                        : bcat[cl];
  }
  asm volatile("s_waitcnt vmcnt(0)" ::: "memory");
  __builtin_amdgcn_sched_barrier(0);

  f32x4 acc[2][3];
#pragma unroll
  for (int i = 0; i < 2; i++)
#pragma unroll
    for (int j = 0; j < 3; j++) acc[i][j] = (f32x4){0.f, 0.f, 0.f, 0.f};

  // stage this wave's (array, slab) unit: 4 loads/wave
#define STG(BUF, K0)                                                             \
  do {                                                                           \
    unsigned short* db = ((arr == 0) ? (Asb + (BUF) * ABUF_H)                    \
                                     : (Bsb + (BUF) * BBUF_H)) + dstoff;         \
    _Pragma("unroll")                                                            \
    for (int i = 0; i < 4; i++)                                                  \
      __builtin_amdgcn_global_load_lds(                                          \
          (const __attribute__((address_space(1))) unsigned int*)(src[i] + (K0)),\
          (__attribute__((address_space(3))) unsigned int*)(db + i * 512),       \
          16, 0, 0);                                                             \
  } while (0)

#define CMP(BUF)                                                                 \
  do {                                                                           \
    const unsigned short* As_ = Asb + (BUF) * ABUF_H;                            \
    const unsigned short* Bs_ = Bsb + (BUF) * BBUF_H;                            \
    _Pragma("unroll")                                                            \
    for (int s = 0; s < 2; s++) {                                                \
      bf16x8 af0 = *(const bf16x8*)&As_[s * 2048 + (rh * 32 + l15) * 32 + qs * 8];      \
      bf16x8 af1 = *(const bf16x8*)&As_[s * 2048 + (rh * 32 + 16 + l15) * 32 + qs * 8]; \
      bf16x8 bfr[3];                                                             \
      _Pragma("unroll")                                                          \
      for (int fi = 0; fi < 3; fi++) {                                           \
        int f = 3 * g + fi;                                                      \
        bfr[fi] = *(const bf16x8*)&Bs_[(f >> 2) * 4096 + s * 2048 +              \
                                       ((f & 3) * 16 + l15) * 32 + qs * 8];      \
      }                                                                          \
      _Pragma("unroll")                                                          \
      for (int fi = 0; fi < 3; fi++) {                                           \
        acc[0][fi] = __builtin_amdgcn_mfma_f32_16x16x32_bf16(af0, bfr[fi], acc[0][fi], 0, 0, 0); \
        acc[1][fi] = __builtin_amdgcn_mfma_f32_16x16x32_bf16(af1, bfr[fi], acc[1][fi], 0, 0, 0); \
      }                                                                          \
    }                                                                            \
  } while (0)

  // prologue: 2 tiles in flight (4 loads each per wave)
  STG(0, 0);
  STG(1, 64);
  // main loop: counted waits — oldest stage complete, next stays in flight
  for (int it = 0; it < 15; it++) {
    asm volatile("s_waitcnt vmcnt(4)" ::: "memory");
    __builtin_amdgcn_sched_barrier(0);
    asm volatile("s_barrier" ::: "memory");          // stage-it data visible everywhere
    CMP(it & 1);
    asm volatile("s_waitcnt lgkmcnt(0)" ::: "memory"); // all ds_reads retired to regs
    __builtin_amdgcn_sched_barrier(0);
    asm volatile("s_barrier" ::: "memory");          // release buffer for restage
    if (it < 14) STG(it & 1, (it + 2) * 64);
  }
  // peeled last iteration: drain fully
  asm volatile("s_waitcnt vmcnt(0)" ::: "memory");
  __builtin_amdgcn_sched_barrier(0);
  asm volatile("s_barrier" ::: "memory");
  CMP(1);
#undef STG
#undef CMP

  // ---- repurpose staging LDS for intra tiles ----
  asm volatile("s_waitcnt lgkmcnt(0)" ::: "memory");  // CMP(1) ds_reads retired
  __builtin_amdgcn_sched_barrier(0);
  __syncthreads();

  unsigned short* Qs  = lds;
  unsigned short* Ks  = lds + 64 * LDP;
  unsigned short* KTs = lds + 2 * 64 * LDP;
  unsigned short* VTs = lds + 3 * 64 * LDP;

  // fragments -> intra tiles (bias applied; K zeroed for pads; Q->Qd for m==0)
#pragma unroll
  for (int fi = 0; fi < 3; fi++) {
    int f = 3 * g + fi, sec = f >> 2;
    int c = (f & 3) * 16 + l15;                        // within-section col 0..63
#pragma unroll
    for (int rb = 0; rb < 2; rb++) {
#pragma unroll
      for (int r = 0; r < 4; r++) {
        int pr = rh * 32 + rb * 16 + quad * 4 + r;
        unsigned short v = f2bf(acc[rb][fi][r] + biasf[fi]);
        if (sec == 0) {
          unsigned short kv = (t0 + pr < L) ? v : (unsigned short)0;
          Ks[pr * LDP + c]  = kv;
          KTs[c * LDP + pr] = kv;
        } else if (sec == 1) {
          VTs[c * LDP + pr] = v;
        } else {
          Qs[pr * LDP + c] = v;
          if (m == 0) Qd[(size_t)((t0 + pr) * BB + b) * HD + c] = v;
        }
      }
    }
  }
  __syncthreads();

  // ---- intra body, split across all 8 waves (R22) ----
  const int* tl = tlist + (size_t)seg * SEGCAP;
  if (w >= 4) {
    // part A: S^T = V^T K -> Sb16 (waves 4-7, wS = w-4)
    const int wS = w - 4;
    const unsigned short* arow = &VTs[(wS * 16 + l15) * LDP];
    bf16x8 a0 = *(const bf16x8*)(arow + quad * 8);
    bf16x8 a1 = *(const bf16x8*)(arow + 32 + quad * 8);
    unsigned short* Sp = Sb16 + ((size_t)seg * NC + chunk) * 4096;
#pragma unroll
    for (int n = 0; n < 4; n++) {
      const unsigned short* brow = &KTs[(n * 16 + l15) * LDP];
      f32x4 a2 = __builtin_amdgcn_mfma_f32_16x16x32_bf16(a0, *(const bf16x8*)(brow + quad * 8),
                                                         (f32x4){0.f,0.f,0.f,0.f}, 0, 0, 0);
      a2 = __builtin_amdgcn_mfma_f32_16x16x32_bf16(a1, *(const bf16x8*)(brow + 32 + quad * 8),
                                                   a2, 0, 0, 0);
#pragma unroll
      for (int r = 0; r < 4; r++)
        Sp[(wS * 16 + quad * 4 + r) * 64 + n * 16 + l15] = f2bf(a2[r]);
    }
  } else {
    // part B: QK^T -> tril(P) -> PV -> scatter (waves 0-3)
    unsigned short* qrow = &Qs[(w * 16 + l15) * LDP];
    bf16x8 aq0 = *(const bf16x8*)(qrow + quad * 8);
    bf16x8 aq1 = *(const bf16x8*)(qrow + 32 + quad * 8);
    f32x4 pp[4];
#pragma unroll
    for (int n = 0; n < 4; n++) {
      const unsigned short* krow = &Ks[(n * 16 + l15) * LDP];
      pp[n] = __builtin_amdgcn_mfma_f32_16x16x32_bf16(aq0, *(const bf16x8*)(krow + quad * 8),
                                                      (f32x4){0.f,0.f,0.f,0.f}, 0, 0, 0);
      pp[n] = __builtin_amdgcn_mfma_f32_16x16x32_bf16(aq1, *(const bf16x8*)(krow + 32 + quad * 8),
                                                      pp[n], 0, 0, 0);
    }
#pragma unroll
    for (int n = 0; n < 4; n++)
#pragma unroll
      for (int r = 0; r < 4; r++) {
        int i = w * 16 + quad * 4 + r, j = n * 16 + l15;
        Qs[i * LDP + j] = (j <= i) ? f2bf(pp[n][r]) : (unsigned short)0;
      }
    bf16x8 ap0 = *(const bf16x8*)(qrow + quad * 8);
    bf16x8 ap1 = *(const bf16x8*)(qrow + 32 + quad * 8);
    f32x4 po[4];
#pragma unroll
    for (int n = 0; n < 4; n++) {
      const unsigned short* vrow = &VTs[(n * 16 + l15) * LDP];
      po[n] = __builtin_amdgcn_mfma_f32_16x16x32_bf16(ap0, *(const bf16x8*)(vrow + quad * 8),
                                                      (f32x4){0.f,0.f,0.f,0.f}, 0, 0, 0);
      po[n] = __builtin_amdgcn_mfma_f32_16x16x32_bf16(ap1, *(const bf16x8*)(vrow + 32 + quad * 8),
                                                      po[n], 0, 0, 0);
    }
#pragma unroll
    for (int r = 0; r < 4; r++) {
      int pos = t0 + w * 16 + quad * 4 + r;
      if (pos < L) {
        int t = tl[pos];
        float alpha = alist[(size_t)seg * SEGCAP + pos];
#pragma unroll
        for (int n = 0; n < 4; n++)
          atomicAdd(&out[(size_t)(t * BB + b) * HD + n * 16 + l15], alpha * po[n][r]);
      }
    }
  }
}

// ---------------------------------------------------------------
// scan: exclusive prefix over active chunks (bf16 in/out, fp32 carry)
// SOFTWARE-PIPELINED. flat grid, batch-pinned.
// ---------------------------------------------------------------
__global__ __launch_bounds__(256) void scan_kernel(
    const float* __restrict__ M0, const int* __restrict__ seglen,
    unsigned short* __restrict__ Sb16) {
  const int batch = blockIdx.x & 7;
  const int idx = blockIdx.x >> 3;
  const int seg = batch * MP1 + (idx >> 2), slab = idx & 3;
  const int nch = (seglen[seg] + CH - 1) / CH;
  if (nch <= 0) return;
  const int tid = threadIdx.x;
  const int off = slab * 1024 + tid * 4;
  float run[4];
#pragma unroll
  for (int u = 0; u < 4; u++) {
    int o = off + u;
    run[u] = M0[(o & 63) * 64 + (o >> 6)];   // M0^T
  }
  unsigned short* base = Sb16 + (size_t)seg * NC * 4096;
  ushort4 s = *(const ushort4*)(base + off);
  for (int c = 0; c < nch; c++) {
    unsigned short* p = base + c * 4096 + off;
    ushort4 snext;
    if (c + 1 < nch) snext = *(const ushort4*)(p + 4096);
    ushort4 o;
    o.x = f2bf(run[0]); o.y = f2bf(run[1]); o.z = f2bf(run[2]); o.w = f2bf(run[3]);
    *(ushort4*)p = o;
    run[0] += bf2f(s.x); run[1] += bf2f(s.y); run[2] += bf2f(s.z); run[3] += bf2f(s.w);
    s = snext;
  }
}

// ---------------------------------------------------------------
// chunk_inter: O = Q @ M_state ; Q gathered from Qd (batch-pinned)
// ---------------------------------------------------------------
__global__ __launch_bounds__(256) void chunk_inter(
    const unsigned short* __restrict__ Qd, const unsigned short* __restrict__ Sb16,
    const int* __restrict__ tlist, const float* __restrict__ alist,
    const int* __restrict__ seglen, float* __restrict__ out) {
  int chunk;
  const int seg = sched_walk(seglen, blockIdx.x, &chunk);
  if (seg < 0) return;
  const int L = seglen[seg];
  const int t0 = chunk * CH;
  __shared__ unsigned short Qs[64 * LDP];
  __shared__ unsigned short MT[64 * LDP];
  const int b = seg / MP1;
  const int tid = threadIdx.x;
  const int* tl = tlist + (size_t)seg * SEGCAP;
  {
    int row = tid >> 2, c16 = (tid & 3) << 4;
    int pos = t0 + row;
    const unsigned short* qb = Qd + (size_t)(tl[pos] * BB + b) * HD;
    *(uint4*)&Qs[row * LDP + c16]     = *(const uint4*)(qb + c16);
    *(uint4*)&Qs[row * LDP + c16 + 8] = *(const uint4*)(qb + c16 + 8);
    const unsigned short* Mp = Sb16 + ((size_t)seg * NC + chunk) * 4096 + row * 64 + c16;
    *(uint4*)&MT[row * LDP + c16]     = *(const uint4*)(Mp);
    *(uint4*)&MT[row * LDP + c16 + 8] = *(const uint4*)(Mp + 8);
  }
  __syncthreads();
  const int lane = tid & 63, w = tid >> 6;
  const int quad = lane >> 4, l15 = lane & 15;
  const unsigned short* qrow = &Qs[(w * 16 + l15) * LDP];
  bf16x8 aq0 = *(const bf16x8*)(qrow + quad * 8);
  bf16x8 aq1 = *(const bf16x8*)(qrow + 32 + quad * 8);
  f32x4 po[4];
#pragma unroll
  for (int n = 0; n < 4; n++) {
    const unsigned short* mrow = &MT[(n * 16 + l15) * LDP];
    po[n] = __builtin_amdgcn_mfma_f32_16x16x32_bf16(aq0, *(const bf16x8*)(mrow + quad * 8),
                                                    (f32x4){0.f,0.f,0.f,0.f}, 0, 0, 0);
    po[n] = __builtin_amdgcn_mfma_f32_16x16x32_bf16(aq1, *(const bf16x8*)(mrow + 32 + quad * 8),
                                                    po[n], 0, 0, 0);
  }
#pragma unroll
  for (int r = 0; r < 4; r++) {
    int pos = t0 + w * 16 + quad * 4 + r;
    if (pos < L) {
      int t = tl[pos];
      float alpha = alist[(size_t)seg * SEGCAP + pos];
#pragma unroll
      for (int n = 0; n < 4; n++)
        atomicAdd(&out[(size_t)(t * BB + b) * HD + n * 16 + l15], alpha * po[n][r]);
    }
  }
}

// ---------------------------------------------------------------
extern "C" void kernel_launch(void* const* d_in, const int* in_sizes, int n_in,
                              void* d_out, int out_size, void* d_ws, size_t ws_size,
                              hipStream_t stream) {
  const float* X  = (const float*)d_in[0];
  const float* M0 = (const float*)d_in[1];
  const float* Wq = (const float*)d_in[2];
  const float* bq = (const float*)d_in[3];
  const float* Wk = (const float*)d_in[4];
  const float* bk = (const float*)d_in[5];
  const float* Wv = (const float*)d_in[6];
  const float* bv = (const float*)d_in[7];
  const float* Wg = (const float*)d_in[8];
  const float* bg = (const float*)d_in[9];

  char* ws = (char*)d_ws;
  unsigned short* Xb   = (unsigned short*)(ws);                  // 33,554,432
  unsigned short* Wt   = (unsigned short*)(ws + 33554432ULL);    //  2,621,440
  float*          bcat = (float*)         (ws + 36175872ULL);    //      5,120
  unsigned short* Qd   = (unsigned short*)(ws + 36180992ULL);    //  2,097,152
  unsigned short* Sb16 = (unsigned short*)(ws + 76026880ULL);    // 18,874,368
  int2*           idxb = (int2*)          (ws + 94901248ULL);    //    131,072
  float2*         alfb = (float2*)        (ws + 95032320ULL);    //    131,072
  int*            tlist= (int*)           (ws + 95163392ULL);    //    589,824
  float*          alist= (float*)         (ws + 95753216ULL);    //    589,824
  int*            slen = (int*)           (ws + 96343040ULL);    //        288

  float* out = (float*)d_out;
  const int n4 = out_size / 4;

  prep<<<320 + NTOK / 16 + NZB, 256, 0, stream>>>(
      X, Wq, Wk, Wv, bq, bk, bv, Wg, bg, Wt, bcat, idxb, alfb, Xb,
      (float4*)out, n4);
  pack_kernel<<<NSEG, 1024, 0, stream>>>(idxb, alfb, tlist, alist, slen);
  pkv_intra<<<1024, 512, 0, stream>>>(Xb, Wt, bcat, tlist, alist, slen, Sb16, Qd, out);
  scan_kernel<<<288, 256, 0, stream>>>(M0, slen, Sb16);
  chunk_inter<<<1024, 256, 0, stream>>>(Qd, Sb16, tlist, alist, slen, out);
}

// Round 26
// 103.676 us; speedup vs baseline: 1.0168x; 1.0168x over previous
//
#include <hip/hip_runtime.h>

#define TT   2048
#define BB   8
#define DD   1024
#define HD   64        // head dim d
#define MP1  9         // NM + 1
#define NTOK (TT*BB)   // 16384
#define CH   64        // chunk length
#define NC   32        // max chunks per segment
#define NSEG (BB*MP1)  // 72 segments
#define SEGCAP 2048    // max packed positions per segment
#define NCAT 1280      // 64 Q + 576 K + 576 V + 64 pad (bcat layout)
#define LDP  72        // padded LDS row stride (16B-aligned)
#define NZB  1024      // zero-out blocks (4MB / (256*16B))

typedef __attribute__((ext_vector_type(8))) short bf16x8;
typedef __attribute__((ext_vector_type(4))) float f32x4;

union U8 { uint4 v; unsigned short s[8]; };

static __device__ __forceinline__ unsigned short f2bf(float f) {
  union { float f; unsigned u; } c; c.f = f;
  unsigned r = (c.u + 0x7FFF + ((c.u >> 16) & 1)) >> 16;   // RNE
  return (unsigned short)r;
}
static __device__ __forceinline__ float bf2f(unsigned short s) {
  union { unsigned u; float f; } c; c.u = ((unsigned)s) << 16;
  return c.f;
}

// schedule walk: flat bid -> (seg, chunk) with batch = bid&7 pinned to XCD
static __device__ __forceinline__ int sched_walk(
    const int* __restrict__ seglen, int bid, int* chunk_out) {
  const int batch = bid & 7;
  int idx = bid >> 3;
  for (int m = 0; m < MP1; m++) {
    int nch = (seglen[batch * MP1 + m] + 63) >> 6;
    if (idx < nch) { *chunk_out = idx; return batch * MP1 + m; }
    idx -= nch;
  }
  return -1;
}

// ---------------------------------------------------------------
// prep (fused, R12): [0,320) weight transpose/cast + bcat;
// [320,1344) gating + X->bf16 batch-major (vectorized Wg staging);
// [1344,2368) zero d_out.
// ---------------------------------------------------------------
__global__ __launch_bounds__(256) void prep(
    const float* __restrict__ X,
    const float* __restrict__ Wq, const float* __restrict__ Wk,
    const float* __restrict__ Wv, const float* __restrict__ bq,
    const float* __restrict__ bk, const float* __restrict__ bv,
    const float* __restrict__ Wg, const float* __restrict__ bg,
    unsigned short* __restrict__ Wt, float* __restrict__ bcat,
    int2* __restrict__ idxb, float2* __restrict__ alfb,
    unsigned short* __restrict__ Xb,
    float4* __restrict__ outz, int n4) {
  __shared__ float smem[8 * DD];
  const int tid = threadIdx.x;
  const int id = blockIdx.x;
  if (id >= 1344) {                         // zero d_out
    int i = (id - 1344) * 256 + tid;
    if (i < n4) outz[i] = make_float4(0.f, 0.f, 0.f, 0.f);
    return;
  }
  if (id < 320) {
    float (*tile)[65] = (float(*)[65])smem;
    const int n0 = (id % 20) * 64, k0 = (id / 20) * 64;
    const int c = tid & 63, rr = tid >> 6;
#pragma unroll 4
    for (int i = 0; i < 16; i++) {
      int kk = k0 + rr * 16 + i;
      int n  = n0 + c;
      float v = 0.f;
      if (n0 < 64)        v = Wq[kk * 64 + n];
      else if (n0 < 640)  v = Wk[kk * 576 + (n - 64)];
      else if (n0 < 1216) v = Wv[kk * 576 + (n - 640)];
      tile[rr * 16 + i][c] = v;
    }
    __syncthreads();
    const int lk = (tid & 15) * 4, ln = tid >> 4;
#pragma unroll
    for (int p = 0; p < 4; p++) {
      int nl = p * 16 + ln;
      ushort4 o;
      o.x = f2bf(tile[lk + 0][nl]); o.y = f2bf(tile[lk + 1][nl]);
      o.z = f2bf(tile[lk + 2][nl]); o.w = f2bf(tile[lk + 3][nl]);
      *(ushort4*)&Wt[(size_t)(n0 + nl) * DD + k0 + lk] = o;
    }
    if (id == 0) {
      for (int idx = tid; idx < NCAT; idx += 256) {
        float b = 0.f;
        if (idx < 64)        b = bq[idx];
        else if (idx < 640)  b = bk[idx - 64];
        else if (idx < 1216) b = bv[idx - 640];
        bcat[idx] = b;
      }
    }
    return;
  }
  // gating: vectorized Wg staging (8 coalesced float4 rounds)
  float* wgT = smem;
#pragma unroll
  for (int idx4 = tid; idx4 < 2048; idx4 += 256) {
    float4 v = *(const float4*)&Wg[(size_t)idx4 * 4];
    int flat = idx4 * 4;
    int i = flat >> 3, j = flat & 7;        // j in {0,4}
    wgT[(j + 0) * DD + i] = v.x;
    wgT[(j + 1) * DD + i] = v.y;
    wgT[(j + 2) * DD + i] = v.z;
    wgT[(j + 3) * DD + i] = v.w;
  }
  __syncthreads();
  const int lane = tid & 63, wave = tid >> 6;
  const int base_tok = (id - 320) * 16 + wave * 4;
  for (int tk = 0; tk < 4; tk++) {
    const int tok = base_tok + tk;                   // tok = t*BB + b
    const float* xr = X + (size_t)tok * DD;
    unsigned short* xbr = Xb + ((size_t)((tok & 7) * TT + (tok >> 3))) * DD;
    float p[8] = {0.f,0.f,0.f,0.f,0.f,0.f,0.f,0.f};
#pragma unroll
    for (int it = 0; it < 4; it++) {
      int i = it * 256 + lane * 4;
      float4 x = *(const float4*)&xr[i];
      ushort4 o;
      o.x = f2bf(x.x); o.y = f2bf(x.y); o.z = f2bf(x.z); o.w = f2bf(x.w);
      *(ushort4*)&xbr[i] = o;
#pragma unroll
      for (int j = 0; j < 8; j++) {
        float4 wv = *(const float4*)&wgT[j * DD + i];
        p[j] += x.x * wv.x + x.y * wv.y + x.z * wv.z + x.w * wv.w;
      }
    }
#pragma unroll
    for (int j = 0; j < 8; j++) {
      float v = p[j];
#pragma unroll
      for (int off = 32; off > 0; off >>= 1) v += __shfl_xor(v, off);
      p[j] = v + bg[j];
    }
    if (lane == 0) {
      int i1 = 0; float z1 = p[0];
#pragma unroll
      for (int j = 1; j < 8; j++) if (p[j] > z1) { z1 = p[j]; i1 = j; }
      int i2 = -1; float z2 = -3.0e38f;
#pragma unroll
      for (int j = 0; j < 8; j++) if (j != i1 && p[j] > z2) { z2 = p[j]; i2 = j; }
      float e   = expf(z2 - z1);
      float inv = 1.0f / (1.0f + e);
      idxb[tok] = make_int2(i1 + 1, i2 + 1);
      alfb[tok] = make_float2(inv, e * inv);
    }
  }
}

// ---------------------------------------------------------------
// pack: per segment (b,m), time-ordered routed token list.
// 1024 threads (16 waves): 2 serial rounds; bit-identical output.
// ---------------------------------------------------------------
__global__ __launch_bounds__(1024) void pack_kernel(
    const int2* __restrict__ idxb, const float2* __restrict__ alfb,
    int* __restrict__ tlist, float* __restrict__ alist,
    int* __restrict__ seglen) {
  const int seg = blockIdx.x;
  const int b = seg / MP1, m = seg % MP1;
  const int tid = threadIdx.x;
  int* tl = tlist + (size_t)seg * SEGCAP;
  float* al = alist + (size_t)seg * SEGCAP;
  if (m == 0) {
    for (int pos = tid; pos < TT; pos += 1024) { tl[pos] = pos; al[pos] = 1.f; }
    if (tid == 0) seglen[seg] = TT;
    return;
  }
  __shared__ int wsum[16];
  const int lane = tid & 63, w = tid >> 6;
  int base = 0;
  for (int r = 0; r < TT / 1024; r++) {
    int t = r * 1024 + tid;
    int2 ix = idxb[t * BB + b];
    bool f = (ix.x == m || ix.y == m);
    float2 af = alfb[t * BB + b];
    float alpha = (ix.x == m) ? af.x : af.y;
    unsigned long long mask = __ballot(f);
    int lanepos = __popcll(mask & ((1ull << lane) - 1ull));
    if (lane == 0) wsum[w] = __popcll(mask);
    __syncthreads();
    int wbase = 0, total = 0;
#pragma unroll
    for (int i = 0; i < 16; i++) { int v = wsum[i]; if (i < w) wbase += v; total += v; }
    if (f) { int pos = base + wbase + lanepos; tl[pos] = t; al[pos] = alpha; }
    base += total;
    __syncthreads();
  }
  if (tid == 0) seglen[seg] = base;
  int Lpad = (base + 63) & ~63;               // pad to GEMM M-tile (BM=64)
  for (int pos = base + tid; pos < Lpad; pos += 1024) { tl[pos] = 0; al[pos] = 0.f; }
}

// ---------------------------------------------------------------
// pkv_intra (FUSED, 512-thread / 8-wave, R22-exact): GEMM phase
// wave -> (array x k-slab) slot-swizzled staging, vmcnt(4) 2-deep
// pipeline; compute wave -> (16-row block x K|V section). Intra
// epilogue split: waves 4-7 part A (S^T = V^T K -> Sb16), waves
// 0-3 part B (QK^T -> tril -> PV -> alpha scatter).
// ---------------------------------------------------------------
#define ABUF_H 4096
#define BBUF_H 12288

__global__ __launch_bounds__(512) void pkv_intra(
    const unsigned short* __restrict__ Xb, const unsigned short* __restrict__ Wt,
    const float* __restrict__ bcat,
    const int* __restrict__ tlist, const float* __restrict__ alist,
    const int* __restrict__ seglen,
    unsigned short* __restrict__ Sb16, unsigned short* __restrict__ Qd,
    float* __restrict__ out) {
  int chunk;
  const int seg = sched_walk(seglen, blockIdx.x, &chunk);
  if (seg < 0) return;
  const int t0 = chunk * 64;
  const int L = seglen[seg];
  const int b = seg / MP1, m = seg % MP1;
  __shared__ unsigned short lds[2 * (ABUF_H + BBUF_H)];   // 64 KB, reused
  __shared__ int tls[64];
  unsigned short* Asb = lds;
  unsigned short* Bsb = lds + 2 * ABUF_H;
  const int tid = threadIdx.x;
  const int lane = tid & 63, w = tid >> 6;          // w in [0,8)
  if (tid < 64) tls[tid] = tlist[(size_t)seg * SEGCAP + t0 + tid];
  __syncthreads();

  // ---- staging assignment: wave -> (array, k-slab) ----
  const int arr = w >> 1;            // 0=A, 1=K, 2=V, 3=Q
  const int sl  = w & 1;             // 32-col k-slab within the 64-tile
  const int lk  = (((lane & 3) ^ ((lane >> 3) & 3))) * 8;  // inverse-swizzled src slot
  const unsigned short* src[4];
#pragma unroll
  for (int i = 0; i < 4; i++) {
    int row = i * 16 + (lane >> 2);
    const unsigned short* p;
    if (arr == 0)      p = Xb + ((size_t)b * TT + tls[row]) * DD;
    else if (arr == 1) p = Wt + (size_t)(64  + m * 64 + row) * DD;
    else if (arr == 2) p = Wt + (size_t)(640 + m * 64 + row) * DD;
    else               p = Wt + (size_t)(row) * DD;
    src[i] = p + sl * 32 + lk;
  }
  const int dstoff = (arr == 0) ? (sl * 2048) : ((arr - 1) * 4096 + sl * 2048);

  // ---- compute assignment: wave -> (16-row block, section) ----
  const int wrB  = (w >> 1) * 16;    // row block 0..3
  const int wc64 = w & 1;            // 0 -> K section, 1 -> V section
  const int quad = lane >> 4, l15 = lane & 15;
  const int qs   = quad ^ ((l15 >> 1) & 3);   // swizzled read slot

  // preload biases and RETIRE them so the pipeline's vmcnt ledger is exact
  float biasv[4], qbias[2];
#pragma unroll
  for (int n = 0; n < 4; n++) {
    int col = wc64 * 64 + n * 16 + l15;
    biasv[n] = bcat[col < 64 ? (64 + m * 64 + col) : (640 + m * 64 + (col - 64))];
  }
#pragma unroll
  for (int i = 0; i < 2; i++) qbias[i] = bcat[wc64 * 32 + i * 16 + l15];
  asm volatile("s_waitcnt vmcnt(0)" ::: "memory");
  __builtin_amdgcn_sched_barrier(0);

  f32x4 acc[4];
  f32x4 qacc[2];
#pragma unroll
  for (int j = 0; j < 4; j++) acc[j] = (f32x4){0.f, 0.f, 0.f, 0.f};
#pragma unroll
  for (int j = 0; j < 2; j++) qacc[j] = (f32x4){0.f, 0.f, 0.f, 0.f};

  // stage this wave's (array, slab) unit: 4 loads/wave
#define STG(BUF, K0)                                                             \
  do {                                                                           \
    unsigned short* db = ((arr == 0) ? (Asb + (BUF) * ABUF_H)                    \
                                     : (Bsb + (BUF) * BBUF_H)) + dstoff;         \
    _Pragma("unroll")                                                            \
    for (int i = 0; i < 4; i++)                                                  \
      __builtin_amdgcn_global_load_lds(                                          \
          (const __attribute__((address_space(1))) unsigned int*)(src[i] + (K0)),\
          (__attribute__((address_space(3))) unsigned int*)(db + i * 512),       \
          16, 0, 0);                                                             \
  } while (0)

#define CMP(BUF)                                                                 \
  do {                                                                           \
    const unsigned short* As_ = Asb + (BUF) * ABUF_H;                            \
    const unsigned short* Bs_ = Bsb + (BUF) * BBUF_H;                            \
    _Pragma("unroll")                                                            \
    for (int s = 0; s < 2; s++) {                                                \
      bf16x8 af = *(const bf16x8*)&As_[s * 2048 + (wrB + l15) * 32 + qs * 8];    \
      bf16x8 bfr[4];                                                             \
      _Pragma("unroll")                                                          \
      for (int n = 0; n < 4; n++)                                                \
        bfr[n] = *(const bf16x8*)&Bs_[wc64 * 4096 + s * 2048 + (n * 16 + l15) * 32 + qs * 8]; \
      _Pragma("unroll")                                                          \
      for (int ni = 0; ni < 4; ni++)                                             \
        acc[ni] = __builtin_amdgcn_mfma_f32_16x16x32_bf16(af, bfr[ni], acc[ni], 0, 0, 0); \
      {                                                                          \
        bf16x8 qf[2];                                                            \
        _Pragma("unroll")                                                        \
        for (int i = 0; i < 2; i++)                                              \
          qf[i] = *(const bf16x8*)&Bs_[8192 + s * 2048 + (wc64 * 32 + i * 16 + l15) * 32 + qs * 8]; \
        _Pragma("unroll")                                                        \
        for (int ni = 0; ni < 2; ni++)                                           \
          qacc[ni] = __builtin_amdgcn_mfma_f32_16x16x32_bf16(af, qf[ni], qacc[ni], 0, 0, 0); \
      }                                                                          \
    }                                                                            \
  } while (0)

  // prologue: 2 tiles in flight (4 loads each per wave)
  STG(0, 0);
  STG(1, 64);
  // main loop: counted waits — oldest stage complete, next stays in flight
  for (int it = 0; it < 15; it++) {
    asm volatile("s_waitcnt vmcnt(4)" ::: "memory");
    __builtin_amdgcn_sched_barrier(0);
    asm volatile("s_barrier" ::: "memory");          // stage-it data visible everywhere
    CMP(it & 1);
    asm volatile("s_waitcnt lgkmcnt(0)" ::: "memory"); // all ds_reads retired to regs
    __builtin_amdgcn_sched_barrier(0);
    asm volatile("s_barrier" ::: "memory");          // release buffer for restage
    if (it < 14) STG(it & 1, (it + 2) * 64);
  }
  // peeled last iteration: drain fully
  asm volatile("s_waitcnt vmcnt(0)" ::: "memory");
  __builtin_amdgcn_sched_barrier(0);
  asm volatile("s_barrier" ::: "memory");
  CMP(1);
#undef STG
#undef CMP

  // ---- repurpose staging LDS for intra tiles ----
  asm volatile("s_waitcnt lgkmcnt(0)" ::: "memory");  // CMP(1) ds_reads retired
  __builtin_amdgcn_sched_barrier(0);
  __syncthreads();

  unsigned short* Qs  = lds;
  unsigned short* Ks  = lds + 64 * LDP;
  unsigned short* KTs = lds + 2 * 64 * LDP;
  unsigned short* VTs = lds + 3 * 64 * LDP;

  // Q fragments -> Qs (bf16, bias applied); m==0 also persists Qd for inter
#pragma unroll
  for (int ni = 0; ni < 2; ni++) {
    int qcol = wc64 * 32 + ni * 16 + l15;              // 0..63
#pragma unroll
    for (int r = 0; r < 4; r++) {
      int pr = wrB + quad * 4 + r;
      unsigned short qv = f2bf(qacc[ni][r] + qbias[ni]);
      Qs[pr * LDP + qcol] = qv;
      if (m == 0) Qd[(size_t)((t0 + pr) * BB + b) * HD + qcol] = qv;
    }
  }
  // K|V fragments -> Ks/KTs (K zeroed for pads) or VTs
#pragma unroll
  for (int ni = 0; ni < 4; ni++) {
    int col = ni * 16 + l15;                           // section-local 0..63
#pragma unroll
    for (int r = 0; r < 4; r++) {
      int pr = wrB + quad * 4 + r;
      unsigned short v = f2bf(acc[ni][r] + biasv[ni]);
      if (wc64 == 0) {
        unsigned short kv = (t0 + pr < L) ? v : (unsigned short)0;
        Ks[pr * LDP + col]  = kv;
        KTs[col * LDP + pr] = kv;
      } else {
        VTs[col * LDP + pr] = v;
      }
    }
  }
  __syncthreads();

  // ---- intra body, split across all 8 waves ----
  const int* tl = tlist + (size_t)seg * SEGCAP;
  if (w >= 4) {
    // part A: S^T = V^T K -> Sb16 (waves 4-7, wS = w-4)
    const int wS = w - 4;
    const unsigned short* arow = &VTs[(wS * 16 + l15) * LDP];
    bf16x8 a0 = *(const bf16x8*)(arow + quad * 8);
    bf16x8 a1 = *(const bf16x8*)(arow + 32 + quad * 8);
    unsigned short* Sp = Sb16 + ((size_t)seg * NC + chunk) * 4096;
#pragma unroll
    for (int n = 0; n < 4; n++) {
      const unsigned short* brow = &KTs[(n * 16 + l15) * LDP];
      f32x4 a2 = __builtin_amdgcn_mfma_f32_16x16x32_bf16(a0, *(const bf16x8*)(brow + quad * 8),
                                                         (f32x4){0.f,0.f,0.f,0.f}, 0, 0, 0);
      a2 = __builtin_amdgcn_mfma_f32_16x16x32_bf16(a1, *(const bf16x8*)(brow + 32 + quad * 8),
                                                   a2, 0, 0, 0);
#pragma unroll
      for (int r = 0; r < 4; r++)
        Sp[(wS * 16 + quad * 4 + r) * 64 + n * 16 + l15] = f2bf(a2[r]);
    }
  } else {
    // part B: QK^T -> tril(P) -> PV -> scatter (waves 0-3)
    unsigned short* qrow = &Qs[(w * 16 + l15) * LDP];
    bf16x8 aq0 = *(const bf16x8*)(qrow + quad * 8);
    bf16x8 aq1 = *(const bf16x8*)(qrow + 32 + quad * 8);
    f32x4 pp[4];
#pragma unroll
    for (int n = 0; n < 4; n++) {
      const unsigned short* krow = &Ks[(n * 16 + l15) * LDP];
      pp[n] = __builtin_amdgcn_mfma_f32_16x16x32_bf16(aq0, *(const bf16x8*)(krow + quad * 8),
                                                      (f32x4){0.f,0.f,0.f,0.f}, 0, 0, 0);
      pp[n] = __builtin_amdgcn_mfma_f32_16x16x32_bf16(aq1, *(const bf16x8*)(krow + 32 + quad * 8),
                                                      pp[n], 0, 0, 0);
    }
#pragma unroll
    for (int n = 0; n < 4; n++)
#pragma unroll
      for (int r = 0; r < 4; r++) {
        int i = w * 16 + quad * 4 + r, j = n * 16 + l15;
        Qs[i * LDP + j] = (j <= i) ? f2bf(pp[n][r]) : (unsigned short)0;
      }
    bf16x8 ap0 = *(const bf16x8*)(qrow + quad * 8);
    bf16x8 ap1 = *(const bf16x8*)(qrow + 32 + quad * 8);
    f32x4 po[4];
#pragma unroll
    for (int n = 0; n < 4; n++) {
      const unsigned short* vrow = &VTs[(n * 16 + l15) * LDP];
      po[n] = __builtin_amdgcn_mfma_f32_16x16x32_bf16(ap0, *(const bf16x8*)(vrow + quad * 8),
                                                      (f32x4){0.f,0.f,0.f,0.f}, 0, 0, 0);
      po[n] = __builtin_amdgcn_mfma_f32_16x16x32_bf16(ap1, *(const bf16x8*)(vrow + 32 + quad * 8),
                                                      po[n], 0, 0, 0);
    }
#pragma unroll
    for (int r = 0; r < 4; r++) {
      int pos = t0 + w * 16 + quad * 4 + r;
      if (pos < L) {
        int t = tl[pos];
        float alpha = alist[(size_t)seg * SEGCAP + pos];
#pragma unroll
        for (int n = 0; n < 4; n++)
          atomicAdd(&out[(size_t)(t * BB + b) * HD + n * 16 + l15], alpha * po[n][r]);
      }
    }
  }
}

// ---------------------------------------------------------------
// scan: exclusive prefix over active chunks (bf16 in/out, fp32 carry)
// SOFTWARE-PIPELINED. flat grid, batch-pinned.
// ---------------------------------------------------------------
__global__ __launch_bounds__(256) void scan_kernel(
    const float* __restrict__ M0, const int* __restrict__ seglen,
    unsigned short* __restrict__ Sb16) {
  const int batch = blockIdx.x & 7;
  const int idx = blockIdx.x >> 3;
  const int seg = batch * MP1 + (idx >> 2), slab = idx & 3;
  const int nch = (seglen[seg] + CH - 1) / CH;
  if (nch <= 0) return;
  const int tid = threadIdx.x;
  const int off = slab * 1024 + tid * 4;
  float run[4];
#pragma unroll
  for (int u = 0; u < 4; u++) {
    int o = off + u;
    run[u] = M0[(o & 63) * 64 + (o >> 6)];   // M0^T
  }
  unsigned short* base = Sb16 + (size_t)seg * NC * 4096;
  ushort4 s = *(const ushort4*)(base + off);
  for (int c = 0; c < nch; c++) {
    unsigned short* p = base + c * 4096 + off;
    ushort4 snext;
    if (c + 1 < nch) snext = *(const ushort4*)(p + 4096);
    ushort4 o;
    o.x = f2bf(run[0]); o.y = f2bf(run[1]); o.z = f2bf(run[2]); o.w = f2bf(run[3]);
    *(ushort4*)p = o;
    run[0] += bf2f(s.x); run[1] += bf2f(s.y); run[2] += bf2f(s.z); run[3] += bf2f(s.w);
    s = snext;
  }
}

// ---------------------------------------------------------------
// chunk_inter: O = Q @ M_state ; Q gathered from Qd (batch-pinned)
// ---------------------------------------------------------------
__global__ __launch_bounds__(256) void chunk_inter(
    const unsigned short* __restrict__ Qd, const unsigned short* __restrict__ Sb16,
    const int* __restrict__ tlist, const float* __restrict__ alist,
    const int* __restrict__ seglen, float* __restrict__ out) {
  int chunk;
  const int seg = sched_walk(seglen, blockIdx.x, &chunk);
  if (seg < 0) return;
  const int L = seglen[seg];
  const int t0 = chunk * CH;
  __shared__ unsigned short Qs[64 * LDP];
  __shared__ unsigned short MT[64 * LDP];
  const int b = seg / MP1;
  const int tid = threadIdx.x;
  const int* tl = tlist + (size_t)seg * SEGCAP;
  {
    int row = tid >> 2, c16 = (tid & 3) << 4;
    int pos = t0 + row;
    const unsigned short* qb = Qd + (size_t)(tl[pos] * BB + b) * HD;
    *(uint4*)&Qs[row * LDP + c16]     = *(const uint4*)(qb + c16);
    *(uint4*)&Qs[row * LDP + c16 + 8] = *(const uint4*)(qb + c16 + 8);
    const unsigned short* Mp = Sb16 + ((size_t)seg * NC + chunk) * 4096 + row * 64 + c16;
    *(uint4*)&MT[row * LDP + c16]     = *(const uint4*)(Mp);
    *(uint4*)&MT[row * LDP + c16 + 8] = *(const uint4*)(Mp + 8);
  }
  __syncthreads();
  const int lane = tid & 63, w = tid >> 6;
  const int quad = lane >> 4, l15 = lane & 15;
  const unsigned short* qrow = &Qs[(w * 16 + l15) * LDP];
  bf16x8 aq0 = *(const bf16x8*)(qrow + quad * 8);
  bf16x8 aq1 = *(const bf16x8*)(qrow + 32 + quad * 8);
  f32x4 po[4];
#pragma unroll
  for (int n = 0; n < 4; n++) {
    const unsigned short* mrow = &MT[(n * 16 + l15) * LDP];
    po[n] = __builtin_amdgcn_mfma_f32_16x16x32_bf16(aq0, *(const bf16x8*)(mrow + quad * 8),
                                                    (f32x4){0.f,0.f,0.f,0.f}, 0, 0, 0);
    po[n] = __builtin_amdgcn_mfma_f32_16x16x32_bf16(aq1, *(const bf16x8*)(mrow + 32 + quad * 8),
                                                    po[n], 0, 0, 0);
  }
#pragma unroll
  for (int r = 0; r < 4; r++) {
    int pos = t0 + w * 16 + quad * 4 + r;
    if (pos < L) {
      int t = tl[pos];
      float alpha = alist[(size_t)seg * SEGCAP + pos];
#pragma unroll
      for (int n = 0; n < 4; n++)
        atomicAdd(&out[(size_t)(t * BB + b) * HD + n * 16 + l15], alpha * po[n][r]);
    }
  }
}

// ---------------------------------------------------------------
extern "C" void kernel_launch(void* const* d_in, const int* in_sizes, int n_in,
                              void* d_out, int out_size, void* d_ws, size_t ws_size,
                              hipStream_t stream) {
  const float* X  = (const float*)d_in[0];
  const float* M0 = (const float*)d_in[1];
  const float* Wq = (const float*)d_in[2];
  const float* bq = (const float*)d_in[3];
  const float* Wk = (const float*)d_in[4];
  const float* bk = (const float*)d_in[5];
  const float* Wv = (const float*)d_in[6];
  const float* bv = (const float*)d_in[7];
  const float* Wg = (const float*)d_in[8];
  const float* bg = (const float*)d_in[9];

  char* ws = (char*)d_ws;
  unsigned short* Xb   = (unsigned short*)(ws);                  // 33,554,432
  unsigned short* Wt   = (unsigned short*)(ws + 33554432ULL);    //  2,621,440
  float*          bcat = (float*)         (ws + 36175872ULL);    //      5,120
  unsigned short* Qd   = (unsigned short*)(ws + 36180992ULL);    //  2,097,152
  unsigned short* Sb16 = (unsigned short*)(ws + 76026880ULL);    // 18,874,368
  int2*           idxb = (int2*)          (ws + 94901248ULL);    //    131,072
  float2*         alfb = (float2*)        (ws + 95032320ULL);    //    131,072
  int*            tlist= (int*)           (ws + 95163392ULL);    //    589,824
  float*          alist= (float*)         (ws + 95753216ULL);    //    589,824
  int*            slen = (int*)           (ws + 96343040ULL);    //        288

  float* out = (float*)d_out;
  const int n4 = out_size / 4;

  prep<<<320 + NTOK / 16 + NZB, 256, 0, stream>>>(
      X, Wq, Wk, Wv, bq, bk, bv, Wg, bg, Wt, bcat, idxb, alfb, Xb,
      (float4*)out, n4);
  pack_kernel<<<NSEG, 1024, 0, stream>>>(idxb, alfb, tlist, alist, slen);
  pkv_intra<<<1024, 512, 0, stream>>>(Xb, Wt, bcat, tlist, alist, slen, Sb16, Qd, out);
  scan_kernel<<<288, 256, 0, stream>>>(M0, slen, Sb16);
  chunk_inter<<<1024, 256, 0, stream>>>(Qd, Sb16, tlist, alist, slen, out);
}